// Round 6
// baseline (378.365 us; speedup 1.0000x reference)
//
#include <hip/hip_runtime.h>
#include <stdint.h>

#define NTOK 2048
#define DIM  1024
#define HID  2048
#define NEXP 8
#define CAP  4224   // 4096 assignments + 128 tile-overflow pad
#define RB   256    // router blocks

typedef __attribute__((ext_vector_type(8))) short short8;
typedef __attribute__((ext_vector_type(4))) float floatx4;
typedef __attribute__((ext_vector_type(4))) unsigned short ushortx4;
typedef __attribute__((ext_vector_type(8))) unsigned short ushortx8;

static __device__ __forceinline__ unsigned short f2bf(float f) {
  uint32_t u = __builtin_bit_cast(uint32_t, f);
  u += 0x7fffu + ((u >> 16) & 1u);   // round-to-nearest-even
  return (unsigned short)(u >> 16);
}

// ---------------- router: fp32 logits -> softmax -> top2 -> weights ----------
__global__ void __launch_bounds__(256) router_kernel(const float* __restrict__ x,
                                                     const float* __restrict__ Wr,
                                                     int* __restrict__ ctrl,
                                                     int* __restrict__ experts,
                                                     float* __restrict__ wts) {
  const int wave = threadIdx.x >> 6;
  const int lane = threadIdx.x & 63;

#pragma unroll
  for (int j = 0; j < 2; j++) {
    int t = blockIdx.x * 8 + wave * 2 + j;
    const float* xr = x + (size_t)t * DIM;
    float acc[NEXP];
#pragma unroll
    for (int e = 0; e < NEXP; e++) acc[e] = 0.f;
#pragma unroll
    for (int i = 0; i < 4; i++) {
      floatx4 v = ((const floatx4*)xr)[i * 64 + lane];
      int idx = (i * 64 + lane) * 4;
#pragma unroll
      for (int e = 0; e < NEXP; e++) {
        floatx4 w = *(const floatx4*)&Wr[e * DIM + idx];
        acc[e] += v.x * w.x + v.y * w.y + v.z * w.z + v.w * w.w;
      }
    }
#pragma unroll
    for (int e = 0; e < NEXP; e++) {
#pragma unroll
      for (int off = 32; off > 0; off >>= 1) acc[e] += __shfl_down(acc[e], off);
    }
    if (lane == 0) {
      float mx = acc[0];
      for (int e = 1; e < NEXP; e++) mx = fmaxf(mx, acc[e]);
      float p[NEXP], s = 0.f;
      for (int e = 0; e < NEXP; e++) { p[e] = expf(acc[e] - mx); s += p[e]; }
      float inv = 1.f / s;
      for (int e = 0; e < NEXP; e++) p[e] *= inv;
      int i0 = 0; float p0 = p[0];
      for (int e = 1; e < NEXP; e++) if (p[e] > p0) { p0 = p[e]; i0 = e; }   // ties: lowest idx
      int i1 = -1; float p1 = -1.f;
      for (int e = 0; e < NEXP; e++) if (e != i0 && p[e] > p1) { p1 = p[e]; i1 = e; }
      float rn = 1.f / (p0 + p1 + 1e-8f);
      experts[2 * t] = i0; experts[2 * t + 1] = i1;
      wts[2 * t] = p0 * rn; wts[2 * t + 1] = p1 * rn;
      atomicAdd(&ctrl[i0], 1);
      atomicAdd(&ctrl[i1], 1);
    }
  }
}

// ---------------- scan: bases + cursors from counts (8 values) ---------------
__global__ void scan_kernel(int* __restrict__ ctrl) {
  if (threadIdx.x == 0) {
    int s = 0;
    for (int e = 0; e < NEXP; e++) { ctrl[8 + e] = s; ctrl[16 + e] = s; s += ctrl[e]; }
  }
}

// ---------------- gather: compact token rows into Xe (bf16) ------------------
__global__ void __launch_bounds__(256) gather_kernel(const float* __restrict__ x,
                                                     int* __restrict__ ctrl,
                                                     const int* __restrict__ experts,
                                                     int* __restrict__ pos,
                                                     unsigned short* __restrict__ Xe) {
  int t = blockIdx.x;
  __shared__ int ps[2];
  if (threadIdx.x == 0) {
    int e0 = experts[2 * t], e1 = experts[2 * t + 1];
    int p0 = atomicAdd(&ctrl[16 + e0], 1);
    int p1 = atomicAdd(&ctrl[16 + e1], 1);
    pos[2 * t] = p0; pos[2 * t + 1] = p1;
    ps[0] = p0; ps[1] = p1;
  }
  __syncthreads();
  int p0 = ps[0], p1 = ps[1];
  int i = threadIdx.x;                         // handles floats 4i..4i+3
  floatx4 v = ((const floatx4*)(x + (size_t)t * DIM))[i];
  ushortx4 b;
  b.x = f2bf(v.x); b.y = f2bf(v.y); b.z = f2bf(v.z); b.w = f2bf(v.w);
  *(ushortx4*)(Xe + (size_t)p0 * DIM + 4 * i) = b;
  *(ushortx4*)(Xe + (size_t)p1 * DIM + 4 * i) = b;
}

// ---- bf16 GEMM with inline fp32->bf16 B-staging, per-expert, B^T layout -----
// A: [CAP x K] bf16 (compacted rows). B: [NEXP*N x K] **fp32** (raw weights).
// B-tiles are loaded fp32 -> VGPR, converted RNE, ds_write_b128 into the same
// XOR-swizzled layout the fragment reads use. No separate convert pass (r3-r5:
// any standalone convert absorbs the harness restore-writeback drain ~86us).
// EPI=0: relu(C)^2 -> bf16 (He).  EPI=1: fp32 store (Ye).
template <int K, int N, int EPI>
__global__ void __launch_bounds__(256) gemm_kernel(const unsigned short* __restrict__ A,
                                                   const float* __restrict__ Bf,
                                                   unsigned short* __restrict__ Cbf,
                                                   float* __restrict__ Cf,
                                                   const int* __restrict__ ctrl) {
  const int e = blockIdx.z;
  const int cnt = ctrl[e];
  const int m0 = blockIdx.y * 128;
  if (m0 >= cnt) return;
  const int base = ctrl[8 + e];
  const int n0 = blockIdx.x * 128;

  __shared__ __align__(16) unsigned short ldsA[128 * 64];
  __shared__ __align__(16) unsigned short ldsB[128 * 64];

  const int tid = threadIdx.x;
  const int lane = tid & 63;
  const int wave = tid >> 6;
  const int wm = wave & 1, wn = wave >> 1;

  const unsigned short* Ae = A + (size_t)(base + m0) * K;
  const float* Be = Bf + ((size_t)e * N + n0) * (size_t)K;

  const int rsub = lane >> 3;   // A-staging: row within 8-row chunk
  const int sg = lane & 7;      // A-staging: stored 16B group (swizzled)
  const int br = tid >> 2;      // B-staging: row within 64-row pass (0..63)
  const int bq = tid & 3;       // B-staging: 16-float strip within the 64-wide k

  floatx4 acc[4][4];
  floatx4 zero = {0.f, 0.f, 0.f, 0.f};
#pragma unroll
  for (int i = 0; i < 4; i++)
#pragma unroll
    for (int j = 0; j < 4; j++) acc[i][j] = zero;

  for (int k0 = 0; k0 < K; k0 += 64) {
    // ---- A: async global->LDS, 16B/lane, XOR-swizzled 16B groups ----
#pragma unroll
    for (int j = 0; j < 4; j++) {
      int c = wave * 4 + j;
      int rc = c * 8 + rsub;
      int g = sg ^ (rc & 7);
      const unsigned short* ga = Ae + (size_t)rc * K + k0 + g * 8;
      __builtin_amdgcn_global_load_lds((const __attribute__((address_space(1))) unsigned int*)ga,
                                       (__attribute__((address_space(3))) unsigned int*)&ldsA[c * 512],
                                       16, 0, 0);
    }
    // ---- B: fp32 global -> VGPR (16 floats/thread/pass, 2 passes) ----
    floatx4 bv[2][4];
#pragma unroll
    for (int p = 0; p < 2; p++) {
      const float* gb = Be + (size_t)(p * 64 + br) * K + k0 + bq * 16;
#pragma unroll
      for (int j = 0; j < 4; j++) bv[p][j] = ((const floatx4*)gb)[j];
    }
    // ---- convert + ds_write_b128 into swizzled layout ----
#pragma unroll
    for (int p = 0; p < 2; p++) {
      int row = p * 64 + br;
#pragma unroll
      for (int j = 0; j < 2; j++) {
        floatx4 u = bv[p][2 * j], w = bv[p][2 * j + 1];
        ushortx8 o;
        o[0] = f2bf(u.x); o[1] = f2bf(u.y); o[2] = f2bf(u.z); o[3] = f2bf(u.w);
        o[4] = f2bf(w.x); o[5] = f2bf(w.y); o[6] = f2bf(w.z); o[7] = f2bf(w.w);
        int g = (bq * 2 + j) ^ (row & 7);
        *(ushortx8*)&ldsB[row * 64 + g * 8] = o;
      }
    }
    __builtin_amdgcn_s_waitcnt(0x0f70);  // vmcnt(0): A asyncs landed in LDS
    __syncthreads();

#pragma unroll
    for (int kk = 0; kk < 2; kk++) {
      int q = lane >> 4;
      int gk = kk * 4 + q;
      short8 af[4], bfr[4];
#pragma unroll
      for (int mi = 0; mi < 4; mi++) {
        int row = wm * 64 + mi * 16 + (lane & 15);
        af[mi] = *(const short8*)&ldsA[row * 64 + (gk ^ (row & 7)) * 8];
      }
#pragma unroll
      for (int ni = 0; ni < 4; ni++) {
        int row = wn * 64 + ni * 16 + (lane & 15);
        bfr[ni] = *(const short8*)&ldsB[row * 64 + (gk ^ (row & 7)) * 8];
      }
#pragma unroll
      for (int mi = 0; mi < 4; mi++)
#pragma unroll
        for (int ni = 0; ni < 4; ni++)
          acc[mi][ni] = __builtin_amdgcn_mfma_f32_16x16x32_bf16(af[mi], bfr[ni], acc[mi][ni], 0, 0, 0);
    }
    __syncthreads();
  }

  // epilogue: D row=(lane>>4)*4+reg, col=lane&15
  // expert segments are packed back-to-back: mask stores past cnt.
  const int lm = lane >> 4;
  const int ln = lane & 15;
#pragma unroll
  for (int mi = 0; mi < 4; mi++) {
#pragma unroll
    for (int ni = 0; ni < 4; ni++) {
#pragma unroll
      for (int r = 0; r < 4; r++) {
        int row = m0 + wm * 64 + mi * 16 + lm * 4 + r;   // local row in expert segment
        if (row < cnt) {
          int col = n0 + wn * 64 + ni * 16 + ln;
          float v = acc[mi][ni][r];
          if (EPI == 0) {
            v = fmaxf(v, 0.f);
            v = v * v;
            Cbf[(size_t)(base + row) * N + col] = f2bf(v);
          } else {
            Cf[(size_t)(base + row) * N + col] = v;
          }
        }
      }
    }
  }
}

// ---------------- combine: out[t] = w0*Ye[p0] + w1*Ye[p1] --------------------
__global__ void __launch_bounds__(256) combine_kernel(const float* __restrict__ Ye,
                                                      const int* __restrict__ pos,
                                                      const float* __restrict__ wts,
                                                      float* __restrict__ out) {
  int t = blockIdx.x;
  int i = threadIdx.x;
  int p0 = pos[2 * t], p1 = pos[2 * t + 1];
  float w0 = wts[2 * t], w1 = wts[2 * t + 1];
  floatx4 y0 = ((const floatx4*)(Ye + (size_t)p0 * DIM))[i];
  floatx4 y1 = ((const floatx4*)(Ye + (size_t)p1 * DIM))[i];
  floatx4 o = y0 * w0 + y1 * w1;
  ((floatx4*)(out + (size_t)t * DIM))[i] = o;
  if (t == 0 && i == 0) out[(size_t)NTOK * DIM] = 0.f;  // aux_loss = 0
}

extern "C" void kernel_launch(void* const* d_in, const int* in_sizes, int n_in,
                              void* d_out, int out_size, void* d_ws, size_t ws_size,
                              hipStream_t stream) {
  const float* x   = (const float*)d_in[0];
  const float* Wr  = (const float*)d_in[1];
  const float* Wfc = (const float*)d_in[2];
  const float* Wpr = (const float*)d_in[3];
  float* out = (float*)d_out;
  char* ws = (char*)d_ws;

  int*   ctrl    = (int*)ws;                          // counts[8] bases[8] cursor[8]
  int*   experts = (int*)(ws + 128);                  // int2 per token
  int*   pos     = (int*)(ws + 128 + 16384);          // int2 per token
  float* wts     = (float*)(ws + 128 + 32768);        // float2 per token
  unsigned short* Xe = (unsigned short*)(ws + 65536); // [CAP x DIM] bf16
  unsigned short* He = Xe + (size_t)CAP * DIM;        // [CAP x HID] bf16
  float*          Ye = (float*)(He + (size_t)CAP * HID);  // [CAP x DIM] f32

  hipMemsetAsync(ws, 0, 128, stream);  // zero counts/bases/cursors

  router_kernel<<<RB, 256, 0, stream>>>(x, Wr, ctrl, experts, wts);
  scan_kernel<<<1, 64, 0, stream>>>(ctrl);
  gather_kernel<<<NTOK, 256, 0, stream>>>(x, ctrl, experts, pos, Xe);

  gemm_kernel<DIM, HID, 0><<<dim3(HID / 128, 16, NEXP), 256, 0, stream>>>(Xe, Wfc, He, nullptr, ctrl);
  gemm_kernel<HID, DIM, 1><<<dim3(DIM / 128, 16, NEXP), 256, 0, stream>>>(He, Wpr, nullptr, Ye, ctrl);

  combine_kernel<<<NTOK, 256, 0, stream>>>(Ye, pos, wts, out);
}

// Round 7
// 375.414 us; speedup vs baseline: 1.0079x; 1.0079x over previous
//
#include <hip/hip_runtime.h>
#include <stdint.h>

#define NTOK 2048
#define DIM  1024
#define HID  2048
#define NEXP 8
#define CAP  4224   // 4096 assignments + 128 tile-overflow pad
#define RB   256    // router blocks

typedef __attribute__((ext_vector_type(8))) short short8;
typedef __attribute__((ext_vector_type(4))) float floatx4;
typedef __attribute__((ext_vector_type(4))) unsigned short ushortx4;
typedef __attribute__((ext_vector_type(8))) unsigned short ushortx8;

static __device__ __forceinline__ unsigned short f2bf(float f) {
  uint32_t u = __builtin_bit_cast(uint32_t, f);
  u += 0x7fffu + ((u >> 16) & 1u);   // round-to-nearest-even
  return (unsigned short)(u >> 16);
}

// ---------------- router: fp32 logits -> softmax -> top2 -> weights ----------
__global__ void __launch_bounds__(256) router_kernel(const float* __restrict__ x,
                                                     const float* __restrict__ Wr,
                                                     int* __restrict__ ctrl,
                                                     int* __restrict__ experts,
                                                     float* __restrict__ wts) {
  const int wave = threadIdx.x >> 6;
  const int lane = threadIdx.x & 63;

#pragma unroll
  for (int j = 0; j < 2; j++) {
    int t = blockIdx.x * 8 + wave * 2 + j;
    const float* xr = x + (size_t)t * DIM;
    float acc[NEXP];
#pragma unroll
    for (int e = 0; e < NEXP; e++) acc[e] = 0.f;
#pragma unroll
    for (int i = 0; i < 4; i++) {
      floatx4 v = ((const floatx4*)xr)[i * 64 + lane];
      int idx = (i * 64 + lane) * 4;
#pragma unroll
      for (int e = 0; e < NEXP; e++) {
        floatx4 w = *(const floatx4*)&Wr[e * DIM + idx];
        acc[e] += v.x * w.x + v.y * w.y + v.z * w.z + v.w * w.w;
      }
    }
#pragma unroll
    for (int e = 0; e < NEXP; e++) {
#pragma unroll
      for (int off = 32; off > 0; off >>= 1) acc[e] += __shfl_down(acc[e], off);
    }
    if (lane == 0) {
      float mx = acc[0];
      for (int e = 1; e < NEXP; e++) mx = fmaxf(mx, acc[e]);
      float p[NEXP], s = 0.f;
      for (int e = 0; e < NEXP; e++) { p[e] = expf(acc[e] - mx); s += p[e]; }
      float inv = 1.f / s;
      for (int e = 0; e < NEXP; e++) p[e] *= inv;
      int i0 = 0; float p0 = p[0];
      for (int e = 1; e < NEXP; e++) if (p[e] > p0) { p0 = p[e]; i0 = e; }   // ties: lowest idx
      int i1 = -1; float p1 = -1.f;
      for (int e = 0; e < NEXP; e++) if (e != i0 && p[e] > p1) { p1 = p[e]; i1 = e; }
      float rn = 1.f / (p0 + p1 + 1e-8f);
      experts[2 * t] = i0; experts[2 * t + 1] = i1;
      wts[2 * t] = p0 * rn; wts[2 * t + 1] = p1 * rn;
      atomicAdd(&ctrl[i0], 1);
      atomicAdd(&ctrl[i1], 1);
    }
  }
}

// ---------------- scan: bases + cursors from counts (8 values) ---------------
__global__ void scan_kernel(int* __restrict__ ctrl) {
  if (threadIdx.x == 0) {
    int s = 0;
    for (int e = 0; e < NEXP; e++) { ctrl[8 + e] = s; ctrl[16 + e] = s; s += ctrl[e]; }
  }
}

// ---------------- gather: compact token rows into Xe (bf16) ------------------
__global__ void __launch_bounds__(256) gather_kernel(const float* __restrict__ x,
                                                     int* __restrict__ ctrl,
                                                     const int* __restrict__ experts,
                                                     int* __restrict__ pos,
                                                     unsigned short* __restrict__ Xe) {
  int t = blockIdx.x;
  __shared__ int ps[2];
  if (threadIdx.x == 0) {
    int e0 = experts[2 * t], e1 = experts[2 * t + 1];
    int p0 = atomicAdd(&ctrl[16 + e0], 1);
    int p1 = atomicAdd(&ctrl[16 + e1], 1);
    pos[2 * t] = p0; pos[2 * t + 1] = p1;
    ps[0] = p0; ps[1] = p1;
  }
  __syncthreads();
  int p0 = ps[0], p1 = ps[1];
  int i = threadIdx.x;                         // handles floats 4i..4i+3
  floatx4 v = ((const floatx4*)(x + (size_t)t * DIM))[i];
  ushortx4 b;
  b.x = f2bf(v.x); b.y = f2bf(v.y); b.z = f2bf(v.z); b.w = f2bf(v.w);
  *(ushortx4*)(Xe + (size_t)p0 * DIM + 4 * i) = b;
  *(ushortx4*)(Xe + (size_t)p1 * DIM + 4 * i) = b;
}

// ---- double-buffered bf16 GEMM, 512 threads, inline fp32->bf16 B-staging ----
// A: [CAP x K] bf16 (compacted rows). B: [NEXP*N x K] fp32 (raw weights).
// 8 waves in a 4x2 grid; each wave owns 32x64 of the 128x128 tile (acc[2][4]).
// One barrier per k-iter: prefetch (A async -> ldsX[nxt], B fp32 -> VGPR) is
// issued BEFORE the MFMA block so load latency hides under compute (r6 showed
// the 2-barrier serial loop at 1-2 blocks/CU is pure latency: 88us, MfmaUtil 8%).
// EPI=0: relu(C)^2 -> bf16 (He).  EPI=1: fp32 store (Ye).
template <int K, int N, int EPI>
__global__ void __launch_bounds__(512, 4) gemm_kernel(const unsigned short* __restrict__ A,
                                                      const float* __restrict__ Bf,
                                                      unsigned short* __restrict__ Cbf,
                                                      float* __restrict__ Cf,
                                                      const int* __restrict__ ctrl) {
  const int e = blockIdx.z;
  const int cnt = ctrl[e];
  const int m0 = blockIdx.y * 128;
  if (m0 >= cnt) return;
  const int base = ctrl[8 + e];
  const int n0 = blockIdx.x * 128;

  __shared__ __align__(16) unsigned short ldsA[2][128 * 64];
  __shared__ __align__(16) unsigned short ldsB[2][128 * 64];

  const int tid = threadIdx.x;
  const int lane = tid & 63;
  const int wave = tid >> 6;           // 0..7
  const int wm = wave >> 1;            // 0..3: 32-row band
  const int wn = wave & 1;             // 0..1: 64-col band

  const unsigned short* Ae = A + (size_t)(base + m0) * K;
  const float* Be = Bf + ((size_t)e * N + n0) * (size_t)K;

  const int rsub = lane >> 3;          // A: row within 8-row chunk
  const int sg = lane & 7;             // A: 16B group (swizzled)
  const int br = tid >> 2;             // B: row 0..127
  const int bq = tid & 3;              // B: 16-float strip

  floatx4 acc[2][4];
  floatx4 zero = {0.f, 0.f, 0.f, 0.f};
#pragma unroll
  for (int i = 0; i < 2; i++)
#pragma unroll
    for (int j = 0; j < 4; j++) acc[i][j] = zero;

  floatx4 bv[4];

  // ---- prologue: stage k-tile 0 into buffer 0 ----
#pragma unroll
  for (int j = 0; j < 2; j++) {
    int c = wave * 2 + j;
    int rc = c * 8 + rsub;
    int g = sg ^ (rc & 7);
    __builtin_amdgcn_global_load_lds(
        (const __attribute__((address_space(1))) unsigned int*)(Ae + (size_t)rc * K + g * 8),
        (__attribute__((address_space(3))) unsigned int*)&ldsA[0][c * 512], 16, 0, 0);
  }
  {
    const float* gb = Be + (size_t)br * K + bq * 16;
#pragma unroll
    for (int j = 0; j < 4; j++) bv[j] = ((const floatx4*)gb)[j];
#pragma unroll
    for (int j = 0; j < 2; j++) {
      floatx4 u = bv[2 * j], w = bv[2 * j + 1];
      ushortx8 o;
      o[0] = f2bf(u.x); o[1] = f2bf(u.y); o[2] = f2bf(u.z); o[3] = f2bf(u.w);
      o[4] = f2bf(w.x); o[5] = f2bf(w.y); o[6] = f2bf(w.z); o[7] = f2bf(w.w);
      int g = (bq * 2 + j) ^ (br & 7);
      *(ushortx8*)&ldsB[0][br * 64 + g * 8] = o;
    }
  }
  __builtin_amdgcn_s_waitcnt(0x0f70);  // vmcnt(0)
  __syncthreads();

  constexpr int NIT = K / 64;
  for (int it = 0; it < NIT; it++) {
    const int cur = it & 1;
    const int nxt = cur ^ 1;
    const int k1 = (it + 1) * 64;
    if (it + 1 < NIT) {
      // prefetch A (async -> LDS nxt) and B (fp32 -> VGPR); latency hides
      // under the MFMA block below.
#pragma unroll
      for (int j = 0; j < 2; j++) {
        int c = wave * 2 + j;
        int rc = c * 8 + rsub;
        int g = sg ^ (rc & 7);
        __builtin_amdgcn_global_load_lds(
            (const __attribute__((address_space(1))) unsigned int*)(Ae + (size_t)rc * K + k1 + g * 8),
            (__attribute__((address_space(3))) unsigned int*)&ldsA[nxt][c * 512], 16, 0, 0);
      }
      const float* gb = Be + (size_t)br * K + k1 + bq * 16;
#pragma unroll
      for (int j = 0; j < 4; j++) bv[j] = ((const floatx4*)gb)[j];
    }
    // ---- compute current buffer ----
#pragma unroll
    for (int kk = 0; kk < 2; kk++) {
      int q = lane >> 4;
      int gk = kk * 4 + q;
      short8 af[2], bfr[4];
#pragma unroll
      for (int mi = 0; mi < 2; mi++) {
        int row = wm * 32 + mi * 16 + (lane & 15);
        af[mi] = *(const short8*)&ldsA[cur][row * 64 + (gk ^ (row & 7)) * 8];
      }
#pragma unroll
      for (int ni = 0; ni < 4; ni++) {
        int row = wn * 64 + ni * 16 + (lane & 15);
        bfr[ni] = *(const short8*)&ldsB[cur][row * 64 + (gk ^ (row & 7)) * 8];
      }
#pragma unroll
      for (int mi = 0; mi < 2; mi++)
#pragma unroll
        for (int ni = 0; ni < 4; ni++)
          acc[mi][ni] = __builtin_amdgcn_mfma_f32_16x16x32_bf16(af[mi], bfr[ni], acc[mi][ni], 0, 0, 0);
    }
    if (it + 1 < NIT) {
      // convert + write prefetched B into nxt; then drain A asyncs.
#pragma unroll
      for (int j = 0; j < 2; j++) {
        floatx4 u = bv[2 * j], w = bv[2 * j + 1];
        ushortx8 o;
        o[0] = f2bf(u.x); o[1] = f2bf(u.y); o[2] = f2bf(u.z); o[3] = f2bf(u.w);
        o[4] = f2bf(w.x); o[5] = f2bf(w.y); o[6] = f2bf(w.z); o[7] = f2bf(w.w);
        int g = (bq * 2 + j) ^ (br & 7);
        *(ushortx8*)&ldsB[nxt][br * 64 + g * 8] = o;
      }
      __builtin_amdgcn_s_waitcnt(0x0f70);  // vmcnt(0): A asyncs for nxt landed
    }
    __syncthreads();
  }

  // epilogue: D row=(lane>>4)*4+reg, col=lane&15
  // expert segments are packed back-to-back: mask stores past cnt.
  const int lm = lane >> 4;
  const int ln = lane & 15;
#pragma unroll
  for (int mi = 0; mi < 2; mi++) {
#pragma unroll
    for (int ni = 0; ni < 4; ni++) {
#pragma unroll
      for (int r = 0; r < 4; r++) {
        int row = m0 + wm * 32 + mi * 16 + lm * 4 + r;   // local row in expert segment
        if (row < cnt) {
          int col = n0 + wn * 64 + ni * 16 + ln;
          float v = acc[mi][ni][r];
          if (EPI == 0) {
            v = fmaxf(v, 0.f);
            v = v * v;
            Cbf[(size_t)(base + row) * N + col] = f2bf(v);
          } else {
            Cf[(size_t)(base + row) * N + col] = v;
          }
        }
      }
    }
  }
}

// ---------------- combine: out[t] = w0*Ye[p0] + w1*Ye[p1] --------------------
__global__ void __launch_bounds__(256) combine_kernel(const float* __restrict__ Ye,
                                                      const int* __restrict__ pos,
                                                      const float* __restrict__ wts,
                                                      float* __restrict__ out) {
  int t = blockIdx.x;
  int i = threadIdx.x;
  int p0 = pos[2 * t], p1 = pos[2 * t + 1];
  float w0 = wts[2 * t], w1 = wts[2 * t + 1];
  floatx4 y0 = ((const floatx4*)(Ye + (size_t)p0 * DIM))[i];
  floatx4 y1 = ((const floatx4*)(Ye + (size_t)p1 * DIM))[i];
  floatx4 o = y0 * w0 + y1 * w1;
  ((floatx4*)(out + (size_t)t * DIM))[i] = o;
  if (t == 0 && i == 0) out[(size_t)NTOK * DIM] = 0.f;  // aux_loss = 0
}

extern "C" void kernel_launch(void* const* d_in, const int* in_sizes, int n_in,
                              void* d_out, int out_size, void* d_ws, size_t ws_size,
                              hipStream_t stream) {
  const float* x   = (const float*)d_in[0];
  const float* Wr  = (const float*)d_in[1];
  const float* Wfc = (const float*)d_in[2];
  const float* Wpr = (const float*)d_in[3];
  float* out = (float*)d_out;
  char* ws = (char*)d_ws;

  int*   ctrl    = (int*)ws;                          // counts[8] bases[8] cursor[8]
  int*   experts = (int*)(ws + 128);                  // int2 per token
  int*   pos     = (int*)(ws + 128 + 16384);          // int2 per token
  float* wts     = (float*)(ws + 128 + 32768);        // float2 per token
  unsigned short* Xe = (unsigned short*)(ws + 65536); // [CAP x DIM] bf16
  unsigned short* He = Xe + (size_t)CAP * DIM;        // [CAP x HID] bf16
  float*          Ye = (float*)(He + (size_t)CAP * HID);  // [CAP x DIM] f32

  hipMemsetAsync(ws, 0, 128, stream);  // zero counts/bases/cursors

  router_kernel<<<RB, 256, 0, stream>>>(x, Wr, ctrl, experts, wts);
  scan_kernel<<<1, 64, 0, stream>>>(ctrl);
  gather_kernel<<<NTOK, 256, 0, stream>>>(x, ctrl, experts, pos, Xe);

  gemm_kernel<DIM, HID, 0><<<dim3(HID / 128, 16, NEXP), 512, 0, stream>>>(Xe, Wfc, He, nullptr, ctrl);
  gemm_kernel<HID, DIM, 1><<<dim3(DIM / 128, 16, NEXP), 512, 0, stream>>>(He, Wpr, nullptr, Ye, ctrl);

  combine_kernel<<<NTOK, 256, 0, stream>>>(Ye, pos, wts, out);
}